// Round 1
// baseline (993.579 us; speedup 1.0000x reference)
//
#include <hip/hip_runtime.h>
#include <stdint.h>

// Top-k (k=64) per row of a [16384, 8192] fp32 matrix, scattered back into a
// dense zero matrix. One wave (64 threads) per row; all data held in VGPRs;
// bitwise radix-select with ballot+scalar-popcount counting (no LDS, no
// barriers); exact tie-break by lowest index (matches jax.lax.top_k).

static constexpr int COLS = 8192;
static constexpr int TPB  = 64;               // one wave per block
static constexpr int NCH  = COLS / (TPB * 4); // 32 float4-chunks per thread
static constexpr int EPT  = NCH * 4;          // 128 elements per thread

// order-preserving float->uint map: larger float => larger uint
__device__ __forceinline__ uint32_t fwd_map(uint32_t f) {
  return f ^ (uint32_t)(((int32_t)f >> 31) | 0x80000000);
}
__device__ __forceinline__ uint32_t inv_map(uint32_t u) {
  uint32_t s = (uint32_t)((int32_t)u >> 31);        // all-ones if top bit set
  return u ^ (0x80000000u | ~s);
}

__global__ __launch_bounds__(TPB) void topk_scatter_kernel(
    const float* __restrict__ x, const int* __restrict__ kptr,
    float* __restrict__ out, int rows) {
  const int row = blockIdx.x;
  if (row >= rows) return;
  const int t = threadIdx.x;
  const int k = kptr[0];

  const uint4* __restrict__ xin =
      reinterpret_cast<const uint4*>(x) + (size_t)row * (COLS / 4);
  uint4* __restrict__ oout =
      reinterpret_cast<uint4*>(out) + (size_t)row * (COLS / 4);

  // ---- load 128 elements/thread into registers, transform to sortable keys
  uint32_t u[EPT];
#pragma unroll
  for (int c = 0; c < NCH; ++c) {
    uint4 v = xin[c * TPB + t];
    u[4 * c + 0] = fwd_map(v.x);
    u[4 * c + 1] = fwd_map(v.y);
    u[4 * c + 2] = fwd_map(v.z);
    u[4 * c + 3] = fwd_map(v.w);
  }

  // ---- bitwise radix select of k-th largest key (wave-uniform scalar state)
  uint32_t prefix = 0;
  for (int b = 31; b >= 0; --b) {
    const uint32_t pivot = prefix | (1u << b);
    int cnt = 0;
#pragma unroll
    for (int e = 0; e < EPT; ++e)
      cnt += __popcll(__ballot(u[e] >= pivot));
    if (cnt == k) { prefix = pivot; break; }  // exactly k survivors: done
    if (cnt > k) prefix = pivot;
  }
  // exact threshold T = min{ u : u >= prefix }  (valid in all exit paths)
  uint32_t mn = 0xFFFFFFFFu;
#pragma unroll
  for (int e = 0; e < EPT; ++e)
    mn = min(mn, (u[e] >= prefix) ? u[e] : 0xFFFFFFFFu);
#pragma unroll
  for (int off = 32; off > 0; off >>= 1)
    mn = min(mn, (uint32_t)__shfl_xor((int)mn, off, 64));
  const uint32_t T = mn;

  // ---- counts vs exact threshold
  int cGT = 0, cEQ = 0;
#pragma unroll
  for (int e = 0; e < EPT; ++e) {
    cGT += __popcll(__ballot(u[e] > T));
    cEQ += __popcll(__ballot(u[e] == T));
  }
  const int r = k - cGT;  // number of ==T elements to take (1 <= r <= cEQ)

  // ---- tie selection: lowest global index first (jax.lax.top_k order)
  uint32_t sel[EPT / 32] = {0u, 0u, 0u, 0u};
  if (cEQ == r) {
    // take all equals (common case: cEQ == r == 1)
#pragma unroll
    for (int e = 0; e < EPT; ++e)
      sel[e >> 5] |= (u[e] == T ? 1u : 0u) << (e & 31);
  } else {
    // global element index of (chunk c, thread t, lane j) = (c*64+t)*4 + j
    // order within chunk: all 4 elems of thread t precede thread t+1's.
    const unsigned long long below = (1ull << t) - 1ull;
    int base = 0;  // wave-uniform running count of equals in earlier chunks
#pragma unroll
    for (int c = 0; c < NCH; ++c) {
      unsigned long long m0 = __ballot(u[4 * c + 0] == T);
      unsigned long long m1 = __ballot(u[4 * c + 1] == T);
      unsigned long long m2 = __ballot(u[4 * c + 2] == T);
      unsigned long long m3 = __ballot(u[4 * c + 3] == T);
      if ((m0 | m1 | m2 | m3) != 0ull) {
        int rk = base + __popcll(m0 & below) + __popcll(m1 & below) +
                 __popcll(m2 & below) + __popcll(m3 & below);
        if ((m0 >> t) & 1) { if (rk < r) sel[(4*c+0) >> 5] |= 1u << ((4*c+0) & 31); ++rk; }
        if ((m1 >> t) & 1) { if (rk < r) sel[(4*c+1) >> 5] |= 1u << ((4*c+1) & 31); ++rk; }
        if ((m2 >> t) & 1) { if (rk < r) sel[(4*c+2) >> 5] |= 1u << ((4*c+2) & 31); ++rk; }
        if ((m3 >> t) & 1) { if (rk < r) sel[(4*c+3) >> 5] |= 1u << ((4*c+3) & 31); ++rk; }
        base += __popcll(m0) + __popcll(m1) + __popcll(m2) + __popcll(m3);
      }
    }
  }

  // ---- write: value if (u > T) or tie-selected, else 0 (poison overwrite)
#pragma unroll
  for (int c = 0; c < NCH; ++c) {
    uint4 o;
    {
      const int e = 4 * c + 0;
      const bool inc = (u[e] > T) | ((sel[e >> 5] >> (e & 31)) & 1u);
      o.x = inc ? inv_map(u[e]) : 0u;
    }
    {
      const int e = 4 * c + 1;
      const bool inc = (u[e] > T) | ((sel[e >> 5] >> (e & 31)) & 1u);
      o.y = inc ? inv_map(u[e]) : 0u;
    }
    {
      const int e = 4 * c + 2;
      const bool inc = (u[e] > T) | ((sel[e >> 5] >> (e & 31)) & 1u);
      o.z = inc ? inv_map(u[e]) : 0u;
    }
    {
      const int e = 4 * c + 3;
      const bool inc = (u[e] > T) | ((sel[e >> 5] >> (e & 31)) & 1u);
      o.w = inc ? inv_map(u[e]) : 0u;
    }
    oout[c * TPB + t] = o;
  }
}

extern "C" void kernel_launch(void* const* d_in, const int* in_sizes, int n_in,
                              void* d_out, int out_size, void* d_ws,
                              size_t ws_size, hipStream_t stream) {
  const float* x = (const float*)d_in[0];
  const int* kp = (const int*)d_in[1];
  float* out = (float*)d_out;
  const int rows = in_sizes[0] / COLS;
  topk_scatter_kernel<<<rows, TPB, 0, stream>>>(x, kp, out, rows);
}